// Round 18
// baseline (179.385 us; speedup 1.0000x reference)
//
#include <hip/hip_runtime.h>

// ---------------------------------------------------------------------------
// Attention forward: out = softmax((X Wq^T + bq)(X Wk^T + bk)^T / 8) (X Wv^T + bv)
// B=2, S=2048, H=1024, NH=16, HD=64.  All matmuls in bf16 MFMA, fp32 accum.
// Round 27 == Round 23 resubmit (R23..R26 never ran: acquisition timeouts).
// R13's addressing theory FALSIFIED on HW (59.1 vs 60.9us).  Decomposition:
// LDS-read pipe is the largest busy component (~45%/iter) because all 4
// waves of a KV-group read IDENTICAL K/V fragments (4x amplification);
// occupancy is register-pinned.  Fix: each wave owns 64 q-rows (jq=4),
// q-tile 256, grid.x=8 (1 block/CU) -> same 16 ds_read_b128/wave-tile feed
// 72 MFMAs instead of 36: LDS bytes per MFMA HALVE.  Staging/swizzles/merge
// topology unchanged (merge in two 128-row rounds).  launch_bounds(512,2).
// qkv_gemm/convert unchanged for attribution.
// ---------------------------------------------------------------------------

typedef __attribute__((ext_vector_type(8))) short bf16x8;
typedef __attribute__((ext_vector_type(4))) float f32x4;

#define L2E 1.44269504088896340736f

__device__ __forceinline__ unsigned short f2bf(float x) {  // RNE
  union { float f; unsigned int u; } a; a.f = x;
  unsigned int r = (a.u + 0x7fffu + ((a.u >> 16) & 1u)) >> 16;
  return (unsigned short)r;
}
__device__ __forceinline__ unsigned int fbits(float x) {
  union { float f; unsigned int u; } a; a.f = x; return a.u;
}

// pack 8 fp32 -> 8 bf16 (A-operand k-order) with HW packed convert if present
__device__ __forceinline__ bf16x8 pack_bf16x8(float p0, float p1, float p2, float p3,
                                              float p4, float p5, float p6, float p7) {
#if defined(__AMDGCN__) && __has_builtin(__builtin_amdgcn_cvt_pk_bf16_f32)
  typedef __attribute__((ext_vector_type(2))) __bf16 bf16x2_t;
  union { bf16x2_t h[4]; bf16x8 v; } pk;
  pk.h[0] = __builtin_amdgcn_cvt_pk_bf16_f32(p0, p1);
  pk.h[1] = __builtin_amdgcn_cvt_pk_bf16_f32(p2, p3);
  pk.h[2] = __builtin_amdgcn_cvt_pk_bf16_f32(p4, p5);
  pk.h[3] = __builtin_amdgcn_cvt_pk_bf16_f32(p6, p7);
  return pk.v;
#else
  unsigned u0 = fbits(p0) + 0x8000u, u1 = fbits(p1) + 0x8000u;
  unsigned u2 = fbits(p2) + 0x8000u, u3 = fbits(p3) + 0x8000u;
  unsigned u4 = fbits(p4) + 0x8000u, u5 = fbits(p5) + 0x8000u;
  unsigned u6 = fbits(p6) + 0x8000u, u7 = fbits(p7) + 0x8000u;
  union { unsigned u[4]; bf16x8 v; } pk;
  pk.u[0] = __builtin_amdgcn_perm(u1, u0, 0x07060302u);
  pk.u[1] = __builtin_amdgcn_perm(u3, u2, 0x07060302u);
  pk.u[2] = __builtin_amdgcn_perm(u5, u4, 0x07060302u);
  pk.u[3] = __builtin_amdgcn_perm(u7, u6, 0x07060302u);
  return pk.v;
#endif
}

__device__ __forceinline__ void gl_lds16(const unsigned short* g, unsigned short* l) {
  __builtin_amdgcn_global_load_lds(
      (const __attribute__((address_space(1))) void*)g,
      (__attribute__((address_space(3))) void*)l, 16, 0, 0);
}

// ---------------------------------------------------------------------------
// Kernel 1: fp32 -> bf16 conversion of hidden + the three weight matrices.
// ---------------------------------------------------------------------------
__global__ __launch_bounds__(256) void convert_all(
    const float* __restrict__ hidden, const float* __restrict__ Wq,
    const float* __restrict__ Wk, const float* __restrict__ Wv,
    unsigned short* __restrict__ Xb, unsigned short* __restrict__ Wqb,
    unsigned short* __restrict__ Wkb, unsigned short* __restrict__ Wvb) {
  int i = blockIdx.x * 256 + threadIdx.x;
  const float* src; unsigned short* dst; int off;
  if (i < 1048576)      { src = hidden; dst = Xb;  off = i; }
  else if (i < 1310720) { src = Wq;     dst = Wqb; off = i - 1048576; }
  else if (i < 1572864) { src = Wk;     dst = Wkb; off = i - 1310720; }
  else                  { src = Wv;     dst = Wvb; off = i - 1572864; }
  float4 v = ((const float4*)src)[off];
  ushort4 o;
  o.x = f2bf(v.x); o.y = f2bf(v.y); o.z = f2bf(v.z); o.w = f2bf(v.w);
  ((ushort4*)dst)[off] = o;
}

// ---------------------------------------------------------------------------
// Kernel 2: QKV projection GEMM.  Out[m,n] = sum_k A[m,k] * B[n,k]  (+bias)
//   z==0: A=X, B=Wq -> Qh [bh][s][d], pre-scaled L2E/8 (softmax fold)
//   z==1: A=X, B=Wk -> Kh [bh][s][d]
//   z==2: A=Wv, B=X -> Vh [bh][d][s]   (V TRANSPOSED, stores stay coalesced)
// 128x128 tile, BK=64, 256 threads, 16B-block XOR swizzle in LDS.
// 1D grid of 768; id&7 ~ XCD: each XCD owns a 1 MB X token-slab in its L2.
// ---------------------------------------------------------------------------
__global__ __launch_bounds__(256) void qkv_gemm(
    const unsigned short* __restrict__ Xb,
    const unsigned short* __restrict__ Wqb, const unsigned short* __restrict__ Wkb,
    const unsigned short* __restrict__ Wvb,
    const float* __restrict__ bq, const float* __restrict__ bk,
    const float* __restrict__ bv,
    unsigned short* __restrict__ Qh, unsigned short* __restrict__ Kh,
    unsigned short* __restrict__ Vh) {
  const int id  = blockIdx.x;          // 0..767
  const int xcd = id & 7;
  const int j   = id >> 3;             // 0..95
  const int tok = xcd * 4 + (j & 3);   // token tile 0..31
  const int k2  = j >> 2;              // 0..23
  const int ft  = k2 & 7;              // feature tile 0..7
  const int z   = k2 >> 3;             // 0..2

  const unsigned short* Ap; const unsigned short* Bp;
  const float* bias; unsigned short* Out; int m0, n0;
  if (z == 2) {
    Ap = Wvb; Bp = Xb; bias = bv; Out = Vh;
    m0 = ft * 128; n0 = tok * 128;     // m: feature, n: token
  } else {
    Ap = Xb; Bp = (z == 0) ? Wqb : Wkb; bias = (z == 0) ? bq : bk;
    Out = (z == 0) ? Qh : Kh;
    m0 = tok * 128; n0 = ft * 128;     // m: token, n: feature
  }
  const float oscale = (z == 0) ? (0.125f * L2E) : 1.0f;

  __shared__ unsigned short As[128 * 64];  // 16 KB
  __shared__ unsigned short Bs[128 * 64];  // 16 KB

  const int tid  = threadIdx.x;
  const int lane = tid & 63;
  const int w    = tid >> 6;
  const int wm   = w >> 1, wn = w & 1;
  const int quad = lane >> 4;
  const int r    = lane & 15;

  f32x4 acc[4][4];
#pragma unroll
  for (int a = 0; a < 4; a++)
#pragma unroll
    for (int c = 0; c < 4; c++) acc[a][c] = (f32x4){0.f, 0.f, 0.f, 0.f};

  for (int k0 = 0; k0 < 1024; k0 += 64) {
    __syncthreads();
#pragma unroll
    for (int i = 0; i < 4; i++) {
      int t   = w * 4 + i;
      int blk = t * 64 + lane;
      int row = blk >> 3;
      int c   = (blk & 7) ^ (row & 7);
      gl_lds16(Ap + (size_t)(m0 + row) * 1024 + k0 + c * 8, &As[t * 512]);
      gl_lds16(Bp + (size_t)(n0 + row) * 1024 + k0 + c * 8, &Bs[t * 512]);
    }
    __syncthreads();

    bf16x8 af[4][2], bfv[4][2];
#pragma unroll
    for (int mi = 0; mi < 4; mi++)
#pragma unroll
      for (int ks = 0; ks < 2; ks++) {
        int row = wm * 64 + mi * 16 + r;
        int bc  = (ks * 4 + quad) ^ (row & 7);
        af[mi][ks] = *(const bf16x8*)&As[row * 64 + bc * 8];
      }
#pragma unroll
    for (int ni = 0; ni < 4; ni++)
#pragma unroll
      for (int ks = 0; ks < 2; ks++) {
        int row = wn * 64 + ni * 16 + r;
        int bc  = (ks * 4 + quad) ^ (row & 7);
        bfv[ni][ks] = *(const bf16x8*)&Bs[row * 64 + bc * 8];
      }
#pragma unroll
    for (int mi = 0; mi < 4; mi++)
#pragma unroll
      for (int ni = 0; ni < 4; ni++) {
        acc[mi][ni] = __builtin_amdgcn_mfma_f32_16x16x32_bf16(af[mi][0], bfv[ni][0], acc[mi][ni], 0, 0, 0);
        acc[mi][ni] = __builtin_amdgcn_mfma_f32_16x16x32_bf16(af[mi][1], bfv[ni][1], acc[mi][ni], 0, 0, 0);
      }
  }

  // epilogue: C/D row = quad*4+e, col = r
  if (z == 2) {
#pragma unroll
    for (int mi = 0; mi < 4; mi++)
#pragma unroll
      for (int e = 0; e < 4; e++) {
        int m = m0 + wm * 64 + mi * 16 + quad * 4 + e;  // feature
        float bm = bias[m];
#pragma unroll
        for (int ni = 0; ni < 4; ni++) {
          int n = n0 + wn * 64 + ni * 16 + r;            // token
          int bb = n >> 11, s = n & 2047;
          int hh = m >> 6,  d = m & 63;
          float v = acc[mi][ni][e] + bm;
          Out[((size_t)(bb * 16 + hh) * 64 + d) * 2048 + s] = f2bf(v);
        }
      }
  } else {
    float biasv[4];
#pragma unroll
    for (int ni = 0; ni < 4; ni++) biasv[ni] = bias[n0 + wn * 64 + ni * 16 + r];
#pragma unroll
    for (int mi = 0; mi < 4; mi++)
#pragma unroll
      for (int ni = 0; ni < 4; ni++)
#pragma unroll
        for (int e = 0; e < 4; e++) {
          int m = m0 + wm * 64 + mi * 16 + quad * 4 + e;  // token
          int n = n0 + wn * 64 + ni * 16 + r;             // feature
          int bb = m >> 11, s = m & 2047;
          int hh = n >> 6,  d = n & 63;
          float v = (acc[mi][ni][e] + biasv[ni]) * oscale;
          Out[((size_t)(bb * 16 + hh) * 2048 + s) * 64 + d] = f2bf(v);
        }
  }
}

// ---------------------------------------------------------------------------
// attn tile compute: boff is a COMPILE-TIME buffer offset (0 or 16384 elems).
// K/V fragments loaded ONCE per ncp and reused across 4 q-subtiles (jq).
// ---------------------------------------------------------------------------
__device__ __forceinline__ void attn_tile(
    const unsigned short* SMbase, int boff,
    const int kfo[2][4], const int vfo[2][4],
    const bf16x8 aq0[4], const bf16x8 aq1[4],
    const bf16x8 ones8, f32x4 lacc[4], f32x4 acc[4][4]) {
  const f32x4 zero4 = (f32x4){0.f, 0.f, 0.f, 0.f};
#pragma unroll
  for (int ncp = 0; ncp < 2; ncp++) {
    bf16x8 kA0 = *(const bf16x8*)&SMbase[kfo[ncp][0] + boff];
    bf16x8 kA1 = *(const bf16x8*)&SMbase[kfo[ncp][1] + boff];
    bf16x8 kB0 = *(const bf16x8*)&SMbase[kfo[ncp][2] + boff];
    bf16x8 kB1 = *(const bf16x8*)&SMbase[kfo[ncp][3] + boff];

    bf16x8 ap8[4];
#pragma unroll
    for (int jq = 0; jq < 4; jq++) {
      // S^T subtile A: lane holds q=r, kv = 8*quad + {0..3} (log2 domain)
      f32x4 tA  = __builtin_amdgcn_mfma_f32_16x16x32_bf16(kA1, aq1[jq], zero4, 0, 0, 0);
      f32x4 sTA = __builtin_amdgcn_mfma_f32_16x16x32_bf16(kA0, aq0[jq], tA, 0, 0, 0);
      // S^T subtile B: kv = 8*quad + {4..7}
      f32x4 tB  = __builtin_amdgcn_mfma_f32_16x16x32_bf16(kB1, aq1[jq], zero4, 0, 0, 0);
      f32x4 sTB = __builtin_amdgcn_mfma_f32_16x16x32_bf16(kB0, aq0[jq], tB, 0, 0, 0);

      float pa0 = __builtin_exp2f(sTA[0]);
      float pa1 = __builtin_exp2f(sTA[1]);
      float pa2 = __builtin_exp2f(sTA[2]);
      float pa3 = __builtin_exp2f(sTA[3]);
      float pb0 = __builtin_exp2f(sTB[0]);
      float pb1 = __builtin_exp2f(sTB[1]);
      float pb2 = __builtin_exp2f(sTB[2]);
      float pb3 = __builtin_exp2f(sTB[3]);
      // A-frag (K=32): lane (r,quad) holds P[q=r][kv = 8*quad + 0..7]
      ap8[jq] = pack_bf16x8(pa0, pa1, pa2, pa3, pb0, pb1, pb2, pb3);
    }

    bf16x8 vf[4];
#pragma unroll
    for (int dc = 0; dc < 4; dc++)
      vf[dc] = *(const bf16x8*)&SMbase[vfo[ncp][dc] + boff];

#pragma unroll
    for (int jq = 0; jq < 4; jq++) {
      lacc[jq] = __builtin_amdgcn_mfma_f32_16x16x32_bf16(ap8[jq], ones8, lacc[jq], 0, 0, 0);
#pragma unroll
      for (int dc = 0; dc < 4; dc++)
        acc[jq][dc] = __builtin_amdgcn_mfma_f32_16x16x32_bf16(ap8[jq], vf[dc], acc[jq][dc], 0, 0, 0);
    }
  }
}

// ---------------------------------------------------------------------------
// Kernel 3: flash attention, in-block split-KV x2, folded static-max softmax,
// register-resident P, all MFMAs K=32 full-rate, double-buffered staging.
// 512 threads = 8 waves: group g = waves [4g,4g+4) handles KV rows
// [g*1024, g*1024+1024) of the SAME 256-row q-tile; wave w%4 owns q rows
// [w*64, w*64+64) (4 fragment pairs -> K/V LDS frags reused 4x: LDS bytes
// per MFMA HALVED vs the 32-row version).
// LDS: [buf][group][K|V] 8 tiles x 8 KB = 64 KB; merge buffer overlays
// (two 128-row merge rounds).  Grid 256 blocks -> 1 block/CU, 8 waves.
// ---------------------------------------------------------------------------
__global__ __launch_bounds__(512, 2) void attn(
    const unsigned short* __restrict__ Qh, const unsigned short* __restrict__ Kh,
    const unsigned short* __restrict__ Vh, float* __restrict__ Out) {
  const int h = blockIdx.y, b = blockIdx.z;
  const int bh = b * 16 + h;
  const int q0 = blockIdx.x * 256;
  const unsigned short* Qp  = Qh + (size_t)bh * 2048 * 64;
  const unsigned short* Kp  = Kh + (size_t)bh * 2048 * 64;
  const unsigned short* VTp = Vh + (size_t)bh * 64 * 2048;   // [d][s]

  // 8 tiles of 64x64 bf16 (8 KB each): [buf][group][K|V].  64 KB total.
  // buf1 = buf0 + 16384 elements (32768 B, folds into ds_read offset).
  __shared__ __align__(16) char SMRAW[65536];
  unsigned short* SMbase = (unsigned short*)SMRAW;

  const int tid  = threadIdx.x;       // 0..511
  const int lane = tid & 63;
  const int w8   = tid >> 6;          // 0..7
  const int half = w8 >> 2;           // KV half (group)
  const int w    = w8 & 3;            // q-subtile (64 rows)
  const int ltid = tid & 255;         // tid within group
  const int quad = lane >> 4;
  const int r    = lane & 15;

  const int kvbase = half * 1024;
  const int gK = half * 8192;         // group K tile base (elements, buf0)
  const int gV = gK + 4096;           // group V tile base

  // ---- staging addresses: precompute once, advance by constant strides ----
  const int blk0 = ltid, blk1 = 256 + ltid;
  const int row0 = blk0 >> 3, cs0 = blk0 & 7;
  const int row1 = blk1 >> 3, cs1 = blk1 & 7;
  const int sk0 = ((row0 >> 3) + 2 * (row0 & 7)) & 7;
  const int sk1 = ((row1 >> 3) + 2 * (row1 & 7)) & 7;
  const unsigned short* gK0 = Kp + (size_t)(kvbase + row0) * 64 + ((cs0 ^ sk0) * 8);
  const unsigned short* gK1 = Kp + (size_t)(kvbase + row1) * 64 + ((cs1 ^ sk1) * 8);
  const unsigned short* gV0 = VTp + (size_t)row0 * 2048 + kvbase + (((cs0 + 5 * row0) & 7) * 8);
  const unsigned short* gV1 = VTp + (size_t)row1 * 2048 + kvbase + (((cs1 + 5 * row1) & 7) * 8);
  const int dKo0 = gK + blk0 * 8, dKo1 = gK + blk1 * 8;
  const int dVo0 = gV + blk0 * 8, dVo1 = gV + blk1 * 8;

#define STAGE(BOFF)                                        \
  do {                                                     \
    gl_lds16(gK0, &SMbase[dKo0 + (BOFF)]);                 \
    gl_lds16(gK1, &SMbase[dKo1 + (BOFF)]);                 \
    gl_lds16(gV0, &SMbase[dVo0 + (BOFF)]);                 \
    gl_lds16(gV1, &SMbase[dVo1 + (BOFF)]);                 \
    gK0 += 64 * 64; gK1 += 64 * 64; gV0 += 64; gV1 += 64;  \
  } while (0)

  // ---- issue first tile's staging before anything else ----
  STAGE(0);

  // ---- fragment LDS offsets (buf0): loop-invariant, computed ONCE ----
  const int prow = ((r >> 2) << 3) + (r & 3);  // permuted K rows (subtile A)
  int kfo[2][4], vfo[2][4];
#pragma unroll
  for (int ncp = 0; ncp < 2; ncp++) {
    const int rowA = ncp * 32 + prow;
    const int rowB = rowA + 4;
    const int sA = ((rowA >> 3) + 2 * (rowA & 7)) & 7;
    const int sB = ((rowB >> 3) + 2 * (rowB & 7)) & 7;
    kfo[ncp][0] = gK + rowA * 64 + ((quad ^ sA) * 8);
    kfo[ncp][1] = gK + rowA * 64 + (((4 + quad) ^ sA) * 8);
    kfo[ncp][2] = gK + rowB * 64 + ((quad ^ sB) * 8);
    kfo[ncp][3] = gK + rowB * 64 + (((4 + quad) ^ sB) * 8);
#pragma unroll
    for (int dc = 0; dc < 4; dc++) {
      const int vrow = dc * 16 + r;
      const int slot = (4 * ncp + quad + 3 * vrow) & 7;
      vfo[ncp][dc] = gV + vrow * 64 + slot * 8;
    }
  }

  // ---- Q fragments direct from global: rows q0 + w*64 + jq*16 + r ----
  const unsigned short* qbase = Qp + (size_t)(q0 + w * 64 + r) * 64 + quad * 8;
  bf16x8 aq0[4], aq1[4];
#pragma unroll
  for (int jq = 0; jq < 4; jq++) {
    aq0[jq] = *(const bf16x8*)(qbase + jq * 16 * 64);
    aq1[jq] = *(const bf16x8*)(qbase + jq * 16 * 64 + 32);
  }

  f32x4 lacc[4];
  f32x4 acc[4][4];
#pragma unroll
  for (int jq = 0; jq < 4; jq++) {
    lacc[jq] = (f32x4){0.f, 0.f, 0.f, 0.f};
#pragma unroll
    for (int dc = 0; dc < 4; dc++) acc[jq][dc] = (f32x4){0.f, 0.f, 0.f, 0.f};
  }

  union { unsigned u[4]; bf16x8 v; } ou;
  ou.u[0] = 0x3F803F80u; ou.u[1] = 0x3F803F80u;
  ou.u[2] = 0x3F803F80u; ou.u[3] = 0x3F803F80u;
  const bf16x8 ones8 = ou.v;                    // B-frag of 1.0 bf16 (K=32)

  __syncthreads();    // first tile staged (implicit vmcnt(0))

  // ---- main loop: 8 unrolled pairs, buf is compile-time in each half ----
#pragma unroll 1
  for (int it = 0; it < 8; ++it) {
    // tile 2it in buf0; prefetch tile 2it+1 -> buf1 (hidden under compute)
    STAGE(16384);
    __builtin_amdgcn_s_setprio(1);
    attn_tile(SMbase, 0, kfo, vfo, aq0, aq1, ones8, lacc, acc);
    __builtin_amdgcn_s_setprio(0);
    __syncthreads();   // implicit vmcnt(0): buf1 resident

    // tile 2it+1 in buf1; prefetch tile 2it+2 -> buf0
    if (it < 7) STAGE(0);
    __builtin_amdgcn_s_setprio(1);
    attn_tile(SMbase, 16384, kfo, vfo, aq0, aq1, ones8, lacc, acc);
    __builtin_amdgcn_s_setprio(0);
    __syncthreads();   // implicit vmcnt(0): buf0 resident
  }
#undef STAGE

  // ---- merge: group 1 -> LDS, group 0 combines and writes.  Two rounds of
  // 128 q-rows (jq {0,1} then {2,3}); Abuf indexed by compact qc, output row
  // s = q0 + w*64 + jq*16 + quad*4 + e.
  float* Abuf = (float*)SMRAW;                  // 128 q x 65 floats (padded)
  float* Lbuf = Abuf + 128 * 65;                // 128 floats
#pragma unroll
  for (int round = 0; round < 2; ++round) {
    __syncthreads();   // (round 0: after main loop; round 1: after reads)
    if (half == 1) {
#pragma unroll
      for (int jq2 = 0; jq2 < 2; jq2++) {
        int jq = round * 2 + jq2;
#pragma unroll
        for (int e = 0; e < 4; e++) {
          int qc = w * 32 + jq2 * 16 + quad * 4 + e;
#pragma unroll
          for (int dc = 0; dc < 4; dc++)
            Abuf[qc * 65 + dc * 16 + r] = acc[jq][dc][e];
          if (r == 0) Lbuf[qc] = lacc[jq][e];
        }
      }
    }
    __syncthreads();
    if (half == 0) {
#pragma unroll
      for (int jq2 = 0; jq2 < 2; jq2++) {
        int jq = round * 2 + jq2;
#pragma unroll
        for (int e = 0; e < 4; e++) {
          int qc = w * 32 + jq2 * 16 + quad * 4 + e;
          float l = lacc[jq][e] + Lbuf[qc];     // total row sum
          float inv = 1.f / l;
          int s = q0 + w * 64 + jq * 16 + quad * 4 + e;
#pragma unroll
          for (int dc = 0; dc < 4; dc++) {
            int d = dc * 16 + r;
            float v = acc[jq][dc][e] + Abuf[qc * 65 + d];
            Out[(size_t)(b * 2048 + s) * 1024 + h * 64 + d] = v * inv;
          }
        }
      }
    }
  }
}

// ---------------------------------------------------------------------------
// Workspace layout (bytes):
//   Qh  @ 0         8388608   [bh][s][d] bf16, pre-scaled L2E/8
//   Kh  @ 8388608   8388608   [bh][s][d] bf16
//   Vh  @ 16777216  8388608   [bh][d][s] bf16 (TRANSPOSED)
//   Xb  @ 25165824  8388608   bf16
//   Wqb @ 33554432  2097152, Wkb @ 35651584, Wvb @ 37748736
//   total 39845888 (~38 MB)
// ---------------------------------------------------------------------------
extern "C" void kernel_launch(void* const* d_in, const int* in_sizes, int n_in,
                              void* d_out, int out_size, void* d_ws, size_t ws_size,
                              hipStream_t stream) {
  const float* hidden = (const float*)d_in[0];
  const float* Wq = (const float*)d_in[1];
  const float* bq = (const float*)d_in[2];
  const float* Wk = (const float*)d_in[3];
  const float* bk = (const float*)d_in[4];
  const float* Wv = (const float*)d_in[5];
  const float* bv = (const float*)d_in[6];
  float* out = (float*)d_out;

  char* ws = (char*)d_ws;
  unsigned short* Qhp = (unsigned short*)(ws + 0);
  unsigned short* Khp = (unsigned short*)(ws + 8388608);
  unsigned short* Vhp = (unsigned short*)(ws + 16777216);
  unsigned short* Xb  = (unsigned short*)(ws + 25165824);
  unsigned short* Wqb = (unsigned short*)(ws + 33554432);
  unsigned short* Wkb = (unsigned short*)(ws + 35651584);
  unsigned short* Wvb = (unsigned short*)(ws + 37748736);

  convert_all<<<7168, 256, 0, stream>>>(hidden, Wq, Wk, Wv, Xb, Wqb, Wkb, Wvb);
  qkv_gemm<<<768, 256, 0, stream>>>(Xb, Wqb, Wkb, Wvb, bq, bk, bv,
                                    Qhp, Khp, Vhp);
  attn<<<dim3(8, 16, 2), 512, 0, stream>>>(Qhp, Khp, Vhp, out);
}

// Round 20
// 178.210 us; speedup vs baseline: 1.0066x; 1.0066x over previous
//
#include <hip/hip_runtime.h>

// ---------------------------------------------------------------------------
// Attention forward: out = softmax((X Wq^T + bq)(X Wk^T + bk)^T / 8) (X Wv^T + bv)
// B=2, S=2048, H=1024, NH=16, HD=64.  All matmuls in bf16 MFMA, fp32 accum.
// Round 29 == Round 28 resubmit (R28 never ran: container infra failure).
// XCD-locality swizzle for attn.  R23 measured: bank conflicts halved but
// dur flat (62.4 vs 59.1) -> LDS was not the wall.  Triangulation of
// R3/R13/R23 (MfmaUtil ~25%, VALUBusy ~55-63%, no pipe saturated, per-CU
// fetch rate 5.9 B/cyc ~= tile period): attn is STALL-BOUND on per-tile K/V
// fetch.  Old grid put XCD = q-tile -> 32 different heads' K/V (16 MB)
// thrash each 4 MB L2, while the 8 blocks sharing a head sit on 8 XCDs.
// Fix: 1D grid of 256, id&7 = XCD group; each XCD serves 4 (b,h) pairs
// (2 MB K/V, L2-resident); all 8 q-blocks of a head on ONE XCD.
// Keeps R23 jq=4 structure (LDS frags reused 4x).  qkv/convert unchanged.
// ---------------------------------------------------------------------------

typedef __attribute__((ext_vector_type(8))) short bf16x8;
typedef __attribute__((ext_vector_type(4))) float f32x4;

#define L2E 1.44269504088896340736f

__device__ __forceinline__ unsigned short f2bf(float x) {  // RNE
  union { float f; unsigned int u; } a; a.f = x;
  unsigned int r = (a.u + 0x7fffu + ((a.u >> 16) & 1u)) >> 16;
  return (unsigned short)r;
}
__device__ __forceinline__ unsigned int fbits(float x) {
  union { float f; unsigned int u; } a; a.f = x; return a.u;
}

// pack 8 fp32 -> 8 bf16 (A-operand k-order) with HW packed convert if present
__device__ __forceinline__ bf16x8 pack_bf16x8(float p0, float p1, float p2, float p3,
                                              float p4, float p5, float p6, float p7) {
#if defined(__AMDGCN__) && __has_builtin(__builtin_amdgcn_cvt_pk_bf16_f32)
  typedef __attribute__((ext_vector_type(2))) __bf16 bf16x2_t;
  union { bf16x2_t h[4]; bf16x8 v; } pk;
  pk.h[0] = __builtin_amdgcn_cvt_pk_bf16_f32(p0, p1);
  pk.h[1] = __builtin_amdgcn_cvt_pk_bf16_f32(p2, p3);
  pk.h[2] = __builtin_amdgcn_cvt_pk_bf16_f32(p4, p5);
  pk.h[3] = __builtin_amdgcn_cvt_pk_bf16_f32(p6, p7);
  return pk.v;
#else
  unsigned u0 = fbits(p0) + 0x8000u, u1 = fbits(p1) + 0x8000u;
  unsigned u2 = fbits(p2) + 0x8000u, u3 = fbits(p3) + 0x8000u;
  unsigned u4 = fbits(p4) + 0x8000u, u5 = fbits(p5) + 0x8000u;
  unsigned u6 = fbits(p6) + 0x8000u, u7 = fbits(p7) + 0x8000u;
  union { unsigned u[4]; bf16x8 v; } pk;
  pk.u[0] = __builtin_amdgcn_perm(u1, u0, 0x07060302u);
  pk.u[1] = __builtin_amdgcn_perm(u3, u2, 0x07060302u);
  pk.u[2] = __builtin_amdgcn_perm(u5, u4, 0x07060302u);
  pk.u[3] = __builtin_amdgcn_perm(u7, u6, 0x07060302u);
  return pk.v;
#endif
}

__device__ __forceinline__ void gl_lds16(const unsigned short* g, unsigned short* l) {
  __builtin_amdgcn_global_load_lds(
      (const __attribute__((address_space(1))) void*)g,
      (__attribute__((address_space(3))) void*)l, 16, 0, 0);
}

// ---------------------------------------------------------------------------
// Kernel 1: fp32 -> bf16 conversion of hidden + the three weight matrices.
// ---------------------------------------------------------------------------
__global__ __launch_bounds__(256) void convert_all(
    const float* __restrict__ hidden, const float* __restrict__ Wq,
    const float* __restrict__ Wk, const float* __restrict__ Wv,
    unsigned short* __restrict__ Xb, unsigned short* __restrict__ Wqb,
    unsigned short* __restrict__ Wkb, unsigned short* __restrict__ Wvb) {
  int i = blockIdx.x * 256 + threadIdx.x;
  const float* src; unsigned short* dst; int off;
  if (i < 1048576)      { src = hidden; dst = Xb;  off = i; }
  else if (i < 1310720) { src = Wq;     dst = Wqb; off = i - 1048576; }
  else if (i < 1572864) { src = Wk;     dst = Wkb; off = i - 1310720; }
  else                  { src = Wv;     dst = Wvb; off = i - 1572864; }
  float4 v = ((const float4*)src)[off];
  ushort4 o;
  o.x = f2bf(v.x); o.y = f2bf(v.y); o.z = f2bf(v.z); o.w = f2bf(v.w);
  ((ushort4*)dst)[off] = o;
}

// ---------------------------------------------------------------------------
// Kernel 2: QKV projection GEMM.  Out[m,n] = sum_k A[m,k] * B[n,k]  (+bias)
//   z==0: A=X, B=Wq -> Qh [bh][s][d], pre-scaled L2E/8 (softmax fold)
//   z==1: A=X, B=Wk -> Kh [bh][s][d]
//   z==2: A=Wv, B=X -> Vh [bh][d][s]   (V TRANSPOSED, stores stay coalesced)
// 128x128 tile, BK=64, 256 threads, 16B-block XOR swizzle in LDS.
// 1D grid of 768; id&7 ~ XCD: each XCD owns a 1 MB X token-slab in its L2.
// ---------------------------------------------------------------------------
__global__ __launch_bounds__(256) void qkv_gemm(
    const unsigned short* __restrict__ Xb,
    const unsigned short* __restrict__ Wqb, const unsigned short* __restrict__ Wkb,
    const unsigned short* __restrict__ Wvb,
    const float* __restrict__ bq, const float* __restrict__ bk,
    const float* __restrict__ bv,
    unsigned short* __restrict__ Qh, unsigned short* __restrict__ Kh,
    unsigned short* __restrict__ Vh) {
  const int id  = blockIdx.x;          // 0..767
  const int xcd = id & 7;
  const int j   = id >> 3;             // 0..95
  const int tok = xcd * 4 + (j & 3);   // token tile 0..31
  const int k2  = j >> 2;              // 0..23
  const int ft  = k2 & 7;              // feature tile 0..7
  const int z   = k2 >> 3;             // 0..2

  const unsigned short* Ap; const unsigned short* Bp;
  const float* bias; unsigned short* Out; int m0, n0;
  if (z == 2) {
    Ap = Wvb; Bp = Xb; bias = bv; Out = Vh;
    m0 = ft * 128; n0 = tok * 128;     // m: feature, n: token
  } else {
    Ap = Xb; Bp = (z == 0) ? Wqb : Wkb; bias = (z == 0) ? bq : bk;
    Out = (z == 0) ? Qh : Kh;
    m0 = tok * 128; n0 = ft * 128;     // m: token, n: feature
  }
  const float oscale = (z == 0) ? (0.125f * L2E) : 1.0f;

  __shared__ unsigned short As[128 * 64];  // 16 KB
  __shared__ unsigned short Bs[128 * 64];  // 16 KB

  const int tid  = threadIdx.x;
  const int lane = tid & 63;
  const int w    = tid >> 6;
  const int wm   = w >> 1, wn = w & 1;
  const int quad = lane >> 4;
  const int r    = lane & 15;

  f32x4 acc[4][4];
#pragma unroll
  for (int a = 0; a < 4; a++)
#pragma unroll
    for (int c = 0; c < 4; c++) acc[a][c] = (f32x4){0.f, 0.f, 0.f, 0.f};

  for (int k0 = 0; k0 < 1024; k0 += 64) {
    __syncthreads();
#pragma unroll
    for (int i = 0; i < 4; i++) {
      int t   = w * 4 + i;
      int blk = t * 64 + lane;
      int row = blk >> 3;
      int c   = (blk & 7) ^ (row & 7);
      gl_lds16(Ap + (size_t)(m0 + row) * 1024 + k0 + c * 8, &As[t * 512]);
      gl_lds16(Bp + (size_t)(n0 + row) * 1024 + k0 + c * 8, &Bs[t * 512]);
    }
    __syncthreads();

    bf16x8 af[4][2], bfv[4][2];
#pragma unroll
    for (int mi = 0; mi < 4; mi++)
#pragma unroll
      for (int ks = 0; ks < 2; ks++) {
        int row = wm * 64 + mi * 16 + r;
        int bc  = (ks * 4 + quad) ^ (row & 7);
        af[mi][ks] = *(const bf16x8*)&As[row * 64 + bc * 8];
      }
#pragma unroll
    for (int ni = 0; ni < 4; ni++)
#pragma unroll
      for (int ks = 0; ks < 2; ks++) {
        int row = wn * 64 + ni * 16 + r;
        int bc  = (ks * 4 + quad) ^ (row & 7);
        bfv[ni][ks] = *(const bf16x8*)&Bs[row * 64 + bc * 8];
      }
#pragma unroll
    for (int mi = 0; mi < 4; mi++)
#pragma unroll
      for (int ni = 0; ni < 4; ni++) {
        acc[mi][ni] = __builtin_amdgcn_mfma_f32_16x16x32_bf16(af[mi][0], bfv[ni][0], acc[mi][ni], 0, 0, 0);
        acc[mi][ni] = __builtin_amdgcn_mfma_f32_16x16x32_bf16(af[mi][1], bfv[ni][1], acc[mi][ni], 0, 0, 0);
      }
  }

  // epilogue: C/D row = quad*4+e, col = r
  if (z == 2) {
#pragma unroll
    for (int mi = 0; mi < 4; mi++)
#pragma unroll
      for (int e = 0; e < 4; e++) {
        int m = m0 + wm * 64 + mi * 16 + quad * 4 + e;  // feature
        float bm = bias[m];
#pragma unroll
        for (int ni = 0; ni < 4; ni++) {
          int n = n0 + wn * 64 + ni * 16 + r;            // token
          int bb = n >> 11, s = n & 2047;
          int hh = m >> 6,  d = m & 63;
          float v = acc[mi][ni][e] + bm;
          Out[((size_t)(bb * 16 + hh) * 64 + d) * 2048 + s] = f2bf(v);
        }
      }
  } else {
    float biasv[4];
#pragma unroll
    for (int ni = 0; ni < 4; ni++) biasv[ni] = bias[n0 + wn * 64 + ni * 16 + r];
#pragma unroll
    for (int mi = 0; mi < 4; mi++)
#pragma unroll
      for (int ni = 0; ni < 4; ni++)
#pragma unroll
        for (int e = 0; e < 4; e++) {
          int m = m0 + wm * 64 + mi * 16 + quad * 4 + e;  // token
          int n = n0 + wn * 64 + ni * 16 + r;             // feature
          int bb = m >> 11, s = m & 2047;
          int hh = n >> 6,  d = n & 63;
          float v = (acc[mi][ni][e] + biasv[ni]) * oscale;
          Out[((size_t)(bb * 16 + hh) * 2048 + s) * 64 + d] = f2bf(v);
        }
  }
}

// ---------------------------------------------------------------------------
// attn tile compute: boff is a COMPILE-TIME buffer offset (0 or 16384 elems).
// K/V fragments loaded ONCE per ncp and reused across 4 q-subtiles (jq).
// ---------------------------------------------------------------------------
__device__ __forceinline__ void attn_tile(
    const unsigned short* SMbase, int boff,
    const int kfo[2][4], const int vfo[2][4],
    const bf16x8 aq0[4], const bf16x8 aq1[4],
    const bf16x8 ones8, f32x4 lacc[4], f32x4 acc[4][4]) {
  const f32x4 zero4 = (f32x4){0.f, 0.f, 0.f, 0.f};
#pragma unroll
  for (int ncp = 0; ncp < 2; ncp++) {
    bf16x8 kA0 = *(const bf16x8*)&SMbase[kfo[ncp][0] + boff];
    bf16x8 kA1 = *(const bf16x8*)&SMbase[kfo[ncp][1] + boff];
    bf16x8 kB0 = *(const bf16x8*)&SMbase[kfo[ncp][2] + boff];
    bf16x8 kB1 = *(const bf16x8*)&SMbase[kfo[ncp][3] + boff];

    bf16x8 ap8[4];
#pragma unroll
    for (int jq = 0; jq < 4; jq++) {
      // S^T subtile A: lane holds q=r, kv = 8*quad + {0..3} (log2 domain)
      f32x4 tA  = __builtin_amdgcn_mfma_f32_16x16x32_bf16(kA1, aq1[jq], zero4, 0, 0, 0);
      f32x4 sTA = __builtin_amdgcn_mfma_f32_16x16x32_bf16(kA0, aq0[jq], tA, 0, 0, 0);
      // S^T subtile B: kv = 8*quad + {4..7}
      f32x4 tB  = __builtin_amdgcn_mfma_f32_16x16x32_bf16(kB1, aq1[jq], zero4, 0, 0, 0);
      f32x4 sTB = __builtin_amdgcn_mfma_f32_16x16x32_bf16(kB0, aq0[jq], tB, 0, 0, 0);

      float pa0 = __builtin_exp2f(sTA[0]);
      float pa1 = __builtin_exp2f(sTA[1]);
      float pa2 = __builtin_exp2f(sTA[2]);
      float pa3 = __builtin_exp2f(sTA[3]);
      float pb0 = __builtin_exp2f(sTB[0]);
      float pb1 = __builtin_exp2f(sTB[1]);
      float pb2 = __builtin_exp2f(sTB[2]);
      float pb3 = __builtin_exp2f(sTB[3]);
      // A-frag (K=32): lane (r,quad) holds P[q=r][kv = 8*quad + 0..7]
      ap8[jq] = pack_bf16x8(pa0, pa1, pa2, pa3, pb0, pb1, pb2, pb3);
    }

    bf16x8 vf[4];
#pragma unroll
    for (int dc = 0; dc < 4; dc++)
      vf[dc] = *(const bf16x8*)&SMbase[vfo[ncp][dc] + boff];

#pragma unroll
    for (int jq = 0; jq < 4; jq++) {
      lacc[jq] = __builtin_amdgcn_mfma_f32_16x16x32_bf16(ap8[jq], ones8, lacc[jq], 0, 0, 0);
#pragma unroll
      for (int dc = 0; dc < 4; dc++)
        acc[jq][dc] = __builtin_amdgcn_mfma_f32_16x16x32_bf16(ap8[jq], vf[dc], acc[jq][dc], 0, 0, 0);
    }
  }
}

// ---------------------------------------------------------------------------
// Kernel 3: flash attention, in-block split-KV x2, folded static-max softmax,
// register-resident P, all MFMAs K=32 full-rate, double-buffered staging.
// 512 threads = 8 waves: group g = waves [4g,4g+4) handles KV rows
// [g*1024, g*1024+1024) of the SAME 256-row q-tile; wave w%4 owns q rows
// [w*64, w*64+64) (4 fragment pairs -> K/V LDS frags reused 4x).
// 1D grid of 256 with XCD-LOCAL decode: id&7 selects the XCD group; each
// XCD serves 4 (b,h) pairs (2 MB K/V -> L2-resident); all 8 q-blocks of a
// head land on ONE XCD so K/V is HBM-fetched once then L2-served.
// LDS: [buf][group][K|V] 8 tiles x 8 KB = 64 KB; merge buffer overlays
// (two 128-row merge rounds).  1 block/CU, 8 waves.
// ---------------------------------------------------------------------------
__global__ __launch_bounds__(512, 2) void attn(
    const unsigned short* __restrict__ Qh, const unsigned short* __restrict__ Kh,
    const unsigned short* __restrict__ Vh, float* __restrict__ Out) {
  // XCD-local decode: id&7 ~ XCD; phi = (b,h) pair; qt = q-tile.
  const int id  = blockIdx.x;            // 0..255
  const int x3  = id & 7;                // ~XCD
  const int j   = id >> 3;               // 0..31
  const int qt  = j & 7;                 // q-tile 0..7
  const int phi = x3 + ((j >> 3) << 3);  // (b,h) pair 0..31
  const int h = phi & 15, b = phi >> 4;
  const int bh = phi;
  const int q0 = qt * 256;
  const unsigned short* Qp  = Qh + (size_t)bh * 2048 * 64;
  const unsigned short* Kp  = Kh + (size_t)bh * 2048 * 64;
  const unsigned short* VTp = Vh + (size_t)bh * 64 * 2048;   // [d][s]

  // 8 tiles of 64x64 bf16 (8 KB each): [buf][group][K|V].  64 KB total.
  // buf1 = buf0 + 16384 elements (32768 B, folds into ds_read offset).
  __shared__ __align__(16) char SMRAW[65536];
  unsigned short* SMbase = (unsigned short*)SMRAW;

  const int tid  = threadIdx.x;       // 0..511
  const int lane = tid & 63;
  const int w8   = tid >> 6;          // 0..7
  const int half = w8 >> 2;           // KV half (group)
  const int w    = w8 & 3;            // q-subtile (64 rows)
  const int ltid = tid & 255;         // tid within group
  const int quad = lane >> 4;
  const int r    = lane & 15;

  const int kvbase = half * 1024;
  const int gK = half * 8192;         // group K tile base (elements, buf0)
  const int gV = gK + 4096;           // group V tile base

  // ---- staging addresses: precompute once, advance by constant strides ----
  const int blk0 = ltid, blk1 = 256 + ltid;
  const int row0 = blk0 >> 3, cs0 = blk0 & 7;
  const int row1 = blk1 >> 3, cs1 = blk1 & 7;
  const int sk0 = ((row0 >> 3) + 2 * (row0 & 7)) & 7;
  const int sk1 = ((row1 >> 3) + 2 * (row1 & 7)) & 7;
  const unsigned short* gK0 = Kp + (size_t)(kvbase + row0) * 64 + ((cs0 ^ sk0) * 8);
  const unsigned short* gK1 = Kp + (size_t)(kvbase + row1) * 64 + ((cs1 ^ sk1) * 8);
  const unsigned short* gV0 = VTp + (size_t)row0 * 2048 + kvbase + (((cs0 + 5 * row0) & 7) * 8);
  const unsigned short* gV1 = VTp + (size_t)row1 * 2048 + kvbase + (((cs1 + 5 * row1) & 7) * 8);
  const int dKo0 = gK + blk0 * 8, dKo1 = gK + blk1 * 8;
  const int dVo0 = gV + blk0 * 8, dVo1 = gV + blk1 * 8;

#define STAGE(BOFF)                                        \
  do {                                                     \
    gl_lds16(gK0, &SMbase[dKo0 + (BOFF)]);                 \
    gl_lds16(gK1, &SMbase[dKo1 + (BOFF)]);                 \
    gl_lds16(gV0, &SMbase[dVo0 + (BOFF)]);                 \
    gl_lds16(gV1, &SMbase[dVo1 + (BOFF)]);                 \
    gK0 += 64 * 64; gK1 += 64 * 64; gV0 += 64; gV1 += 64;  \
  } while (0)

  // ---- issue first tile's staging before anything else ----
  STAGE(0);

  // ---- fragment LDS offsets (buf0): loop-invariant, computed ONCE ----
  const int prow = ((r >> 2) << 3) + (r & 3);  // permuted K rows (subtile A)
  int kfo[2][4], vfo[2][4];
#pragma unroll
  for (int ncp = 0; ncp < 2; ncp++) {
    const int rowA = ncp * 32 + prow;
    const int rowB = rowA + 4;
    const int sA = ((rowA >> 3) + 2 * (rowA & 7)) & 7;
    const int sB = ((rowB >> 3) + 2 * (rowB & 7)) & 7;
    kfo[ncp][0] = gK + rowA * 64 + ((quad ^ sA) * 8);
    kfo[ncp][1] = gK + rowA * 64 + (((4 + quad) ^ sA) * 8);
    kfo[ncp][2] = gK + rowB * 64 + ((quad ^ sB) * 8);
    kfo[ncp][3] = gK + rowB * 64 + (((4 + quad) ^ sB) * 8);
#pragma unroll
    for (int dc = 0; dc < 4; dc++) {
      const int vrow = dc * 16 + r;
      const int slot = (4 * ncp + quad + 3 * vrow) & 7;
      vfo[ncp][dc] = gV + vrow * 64 + slot * 8;
    }
  }

  // ---- Q fragments direct from global: rows q0 + w*64 + jq*16 + r ----
  const unsigned short* qbase = Qp + (size_t)(q0 + w * 64 + r) * 64 + quad * 8;
  bf16x8 aq0[4], aq1[4];
#pragma unroll
  for (int jq = 0; jq < 4; jq++) {
    aq0[jq] = *(const bf16x8*)(qbase + jq * 16 * 64);
    aq1[jq] = *(const bf16x8*)(qbase + jq * 16 * 64 + 32);
  }

  f32x4 lacc[4];
  f32x4 acc[4][4];
#pragma unroll
  for (int jq = 0; jq < 4; jq++) {
    lacc[jq] = (f32x4){0.f, 0.f, 0.f, 0.f};
#pragma unroll
    for (int dc = 0; dc < 4; dc++) acc[jq][dc] = (f32x4){0.f, 0.f, 0.f, 0.f};
  }

  union { unsigned u[4]; bf16x8 v; } ou;
  ou.u[0] = 0x3F803F80u; ou.u[1] = 0x3F803F80u;
  ou.u[2] = 0x3F803F80u; ou.u[3] = 0x3F803F80u;
  const bf16x8 ones8 = ou.v;                    // B-frag of 1.0 bf16 (K=32)

  __syncthreads();    // first tile staged (implicit vmcnt(0))

  // ---- main loop: 8 unrolled pairs, buf is compile-time in each half ----
#pragma unroll 1
  for (int it = 0; it < 8; ++it) {
    // tile 2it in buf0; prefetch tile 2it+1 -> buf1 (hidden under compute)
    STAGE(16384);
    __builtin_amdgcn_s_setprio(1);
    attn_tile(SMbase, 0, kfo, vfo, aq0, aq1, ones8, lacc, acc);
    __builtin_amdgcn_s_setprio(0);
    __syncthreads();   // implicit vmcnt(0): buf1 resident

    // tile 2it+1 in buf1; prefetch tile 2it+2 -> buf0
    if (it < 7) STAGE(0);
    __builtin_amdgcn_s_setprio(1);
    attn_tile(SMbase, 16384, kfo, vfo, aq0, aq1, ones8, lacc, acc);
    __builtin_amdgcn_s_setprio(0);
    __syncthreads();   // implicit vmcnt(0): buf0 resident
  }
#undef STAGE

  // ---- merge: group 1 -> LDS, group 0 combines and writes.  Two rounds of
  // 128 q-rows (jq {0,1} then {2,3}); Abuf indexed by compact qc, output row
  // s = q0 + w*64 + jq*16 + quad*4 + e.
  float* Abuf = (float*)SMRAW;                  // 128 q x 65 floats (padded)
  float* Lbuf = Abuf + 128 * 65;                // 128 floats
#pragma unroll
  for (int round = 0; round < 2; ++round) {
    __syncthreads();   // (round 0: after main loop; round 1: after reads)
    if (half == 1) {
#pragma unroll
      for (int jq2 = 0; jq2 < 2; jq2++) {
        int jq = round * 2 + jq2;
#pragma unroll
        for (int e = 0; e < 4; e++) {
          int qc = w * 32 + jq2 * 16 + quad * 4 + e;
#pragma unroll
          for (int dc = 0; dc < 4; dc++)
            Abuf[qc * 65 + dc * 16 + r] = acc[jq][dc][e];
          if (r == 0) Lbuf[qc] = lacc[jq][e];
        }
      }
    }
    __syncthreads();
    if (half == 0) {
#pragma unroll
      for (int jq2 = 0; jq2 < 2; jq2++) {
        int jq = round * 2 + jq2;
#pragma unroll
        for (int e = 0; e < 4; e++) {
          int qc = w * 32 + jq2 * 16 + quad * 4 + e;
          float l = lacc[jq][e] + Lbuf[qc];     // total row sum
          float inv = 1.f / l;
          int s = q0 + w * 64 + jq * 16 + quad * 4 + e;
#pragma unroll
          for (int dc = 0; dc < 4; dc++) {
            int d = dc * 16 + r;
            float v = acc[jq][dc][e] + Abuf[qc * 65 + d];
            Out[(size_t)(b * 2048 + s) * 1024 + h * 64 + d] = v * inv;
          }
        }
      }
    }
  }
}

// ---------------------------------------------------------------------------
// Workspace layout (bytes):
//   Qh  @ 0         8388608   [bh][s][d] bf16, pre-scaled L2E/8
//   Kh  @ 8388608   8388608   [bh][s][d] bf16
//   Vh  @ 16777216  8388608   [bh][d][s] bf16 (TRANSPOSED)
//   Xb  @ 25165824  8388608   bf16
//   Wqb @ 33554432  2097152, Wkb @ 35651584, Wvb @ 37748736
//   total 39845888 (~38 MB)
// ---------------------------------------------------------------------------
extern "C" void kernel_launch(void* const* d_in, const int* in_sizes, int n_in,
                              void* d_out, int out_size, void* d_ws, size_t ws_size,
                              hipStream_t stream) {
  const float* hidden = (const float*)d_in[0];
  const float* Wq = (const float*)d_in[1];
  const float* bq = (const float*)d_in[2];
  const float* Wk = (const float*)d_in[3];
  const float* bk = (const float*)d_in[4];
  const float* Wv = (const float*)d_in[5];
  const float* bv = (const float*)d_in[6];
  float* out = (float*)d_out;

  char* ws = (char*)d_ws;
  unsigned short* Qhp = (unsigned short*)(ws + 0);
  unsigned short* Khp = (unsigned short*)(ws + 8388608);
  unsigned short* Vhp = (unsigned short*)(ws + 16777216);
  unsigned short* Xb  = (unsigned short*)(ws + 25165824);
  unsigned short* Wqb = (unsigned short*)(ws + 33554432);
  unsigned short* Wkb = (unsigned short*)(ws + 35651584);
  unsigned short* Wvb = (unsigned short*)(ws + 37748736);

  convert_all<<<7168, 256, 0, stream>>>(hidden, Wq, Wk, Wv, Xb, Wqb, Wkb, Wvb);
  qkv_gemm<<<768, 256, 0, stream>>>(Xb, Wqb, Wkb, Wvb, bq, bk, bv,
                                    Qhp, Khp, Vhp);
  attn<<<256, 512, 0, stream>>>(Qhp, Khp, Vhp, out);
}